// Round 16
// baseline (346.230 us; speedup 1.0000x reference)
//
#include <hip/hip_runtime.h>

using short8 = __attribute__((ext_vector_type(8))) short;
using f32x4  = __attribute__((ext_vector_type(4))) float;
using f32x16 = __attribute__((ext_vector_type(16))) float;
using u16x4  = __attribute__((ext_vector_type(4))) unsigned short;
using fl4    = __attribute__((ext_vector_type(4))) float;

#define MFMA16(a, b, c) __builtin_amdgcn_mfma_f32_16x16x32_bf16((a), (b), (c), 0, 0, 0)
#define MFMA32(a, b, c) __builtin_amdgcn_mfma_f32_32x32x16_bf16((a), (b), (c), 0, 0, 0)

static __device__ __forceinline__ unsigned short f2bf(float f) {
  union { float f; unsigned u; } x; x.f = f;
  return (unsigned short)((x.u + 0x7FFFu + ((x.u >> 16) & 1u)) >> 16);
}
static __device__ __forceinline__ float bf2f(unsigned short s) {
  union { unsigned u; float f; } x; x.u = ((unsigned)s) << 16;
  return x.f;
}
// v_exp_f32 computes 2^x directly (input pre-scaled by log2e upstream)
static __device__ __forceinline__ float fexp2(float x) {
  float r; asm("v_exp_f32 %0, %1" : "=v"(r) : "v"(x)); return r;
}
// packed f32x2 -> bf16x2 (RNE), T12 recipe
static __device__ __forceinline__ unsigned pk2(float lo, float hi) {
  unsigned r; asm("v_cvt_pk_bf16_f32 %0, %1, %2" : "=v"(r) : "v"(lo), "v"(hi));
  return r;
}

// async global->LDS, 16B per lane; lds base must be wave-uniform.
static __device__ __forceinline__ void gload16(const void* g, void* l) {
  __builtin_amdgcn_global_load_lds((const __attribute__((address_space(1))) void*)g,
                                   (__attribute__((address_space(3))) void*)l, 16, 0, 0);
}

#define LOG2E 1.4426950408889634f

// ---------------------------------------------------------------------------
// Prep (fused): blocks [0,1024): Wt[n][k]=bf16(W[k][n]) for 4 weights;
//               blocks [1024,9216): f32->bf16 bulk convert of q and v.
// ---------------------------------------------------------------------------
__global__ __launch_bounds__(256) void k_prep(
    const float* __restrict__ W0, const float* __restrict__ W1,
    const float* __restrict__ W2, const float* __restrict__ W3,
    unsigned short* __restrict__ Wt0, unsigned short* __restrict__ Wt1,
    unsigned short* __restrict__ Wt2, unsigned short* __restrict__ Wt3,
    const float* __restrict__ qf, const float* __restrict__ vf,
    unsigned short* __restrict__ QB, unsigned short* __restrict__ VB) {
  __shared__ float tile[64][65];
  const int bx = blockIdx.x;
  const int t = threadIdx.x;
  if (bx < 1024) {
    const int z = bx >> 8, yy = (bx >> 4) & 15, xx = bx & 15;
    const float* W = (z == 0) ? W0 : (z == 1) ? W1 : (z == 2) ? W2 : W3;
    unsigned short* Wt = (z == 0) ? Wt0 : (z == 1) ? Wt1 : (z == 2) ? Wt2 : Wt3;
    const int n0 = xx * 64, k0 = yy * 64;
#pragma unroll
    for (int p = 0; p < 4; ++p) {
      int row = p * 16 + (t >> 4);
      int c4 = (t & 15) * 4;
      fl4 val = *(const fl4*)&W[(size_t)(k0 + row) * 1024 + n0 + c4];
      tile[row][c4 + 0] = val[0];
      tile[row][c4 + 1] = val[1];
      tile[row][c4 + 2] = val[2];
      tile[row][c4 + 3] = val[3];
    }
    __syncthreads();
#pragma unroll
    for (int p = 0; p < 4; ++p) {
      int n = p * 16 + (t >> 4);
      int k4 = (t & 15) * 4;
      u16x4 u;
      u[0] = f2bf(tile[k4 + 0][n]);
      u[1] = f2bf(tile[k4 + 1][n]);
      u[2] = f2bf(tile[k4 + 2][n]);
      u[3] = f2bf(tile[k4 + 3][n]);
      *(u16x4*)&Wt[(size_t)(n0 + n) * 1024 + k0 + k4] = u;
    }
  } else {
    const int idx = bx - 1024;           // 0..8191
    const int half = idx >> 12;          // 0: q, 1: v
    const int blk = idx & 4095;
    const float* src = half ? vf : qf;
    unsigned short* dst = half ? VB : QB;
    size_t i = ((size_t)blk * 256 + t) * 8;
    fl4 v0 = *(const fl4*)&src[i];
    fl4 v1 = *(const fl4*)&src[i + 4];
    u16x4 u0, u1;
    u0[0] = f2bf(v0[0]); u0[1] = f2bf(v0[1]); u0[2] = f2bf(v0[2]); u0[3] = f2bf(v0[3]);
    u1[0] = f2bf(v1[0]); u1[1] = f2bf(v1[1]); u1[2] = f2bf(v1[2]); u1[3] = f2bf(v1[3]);
    *(u16x4*)&dst[i] = u0;
    *(u16x4*)&dst[i + 4] = u1;
  }
}

// ---------------------------------------------------------------------------
// Q projection (GEMM3 3-buf ring, counted vmcnt): QW = (q@Wq+bq)*log2e/8
// XCD locality: grid (64 m0, 8 n0) -> same-A blocks co-XCD.
// ---------------------------------------------------------------------------
__global__ __launch_bounds__(256) void k_projQ(
    const unsigned short* __restrict__ QB, const unsigned short* __restrict__ WtQ,
    const float* __restrict__ bq, unsigned short* __restrict__ QW) {
  const int m0 = blockIdx.x * 128, n0 = blockIdx.y * 128;
  const int t = threadIdx.x, lane = t & 63, w = t >> 6;
  const int g = lane >> 4, ln = lane & 15;
  const int wm = w >> 1, wn = w & 1;
  __shared__ unsigned short sh[24576];  // 3 bufs x (A 4096 + B 4096)
  const int srow = lane >> 2;
  const int sc = (lane & 3) ^ ((lane >> 3) & 3);
  const int rsw = ((ln >> 1) & 3);
  f32x4 acc[4][4] = {};
#pragma unroll
  for (int pre = 0; pre < 2; ++pre) {
#pragma unroll
    for (int p = 0; p < 2; ++p) {
      gload16(&QB[(size_t)(m0 + p * 64 + w * 16 + srow) * 1024 + pre * 32 + sc * 8],
              &sh[pre * 8192 + (p * 64 + w * 16) * 32]);
      gload16(&WtQ[(size_t)(n0 + p * 64 + w * 16 + srow) * 1024 + pre * 32 + sc * 8],
              &sh[pre * 8192 + 4096 + (p * 64 + w * 16) * 32]);
    }
  }
  int cur = 0;
  for (int tt = 0; tt < 32; ++tt) {
    if (tt < 31) {
      asm volatile("s_waitcnt vmcnt(4)" ::: "memory");
    } else {
      asm volatile("s_waitcnt vmcnt(0)" ::: "memory");
    }
    __builtin_amdgcn_sched_barrier(0);
    __builtin_amdgcn_s_barrier();
    __builtin_amdgcn_sched_barrier(0);
    if (tt < 30) {
      int bb = cur + 2; if (bb >= 3) bb -= 3;
      int kk = (tt + 2) * 32;
#pragma unroll
      for (int p = 0; p < 2; ++p) {
        gload16(&QB[(size_t)(m0 + p * 64 + w * 16 + srow) * 1024 + kk + sc * 8],
                &sh[bb * 8192 + (p * 64 + w * 16) * 32]);
        gload16(&WtQ[(size_t)(n0 + p * 64 + w * 16 + srow) * 1024 + kk + sc * 8],
                &sh[bb * 8192 + 4096 + (p * 64 + w * 16) * 32]);
      }
    }
    const unsigned short* As = &sh[cur * 8192];
    const unsigned short* Bs = As + 4096;
    short8 af[4], bfr[4];
#pragma unroll
    for (int fm = 0; fm < 4; ++fm)
      af[fm] = *(const short8*)&As[(wm * 64 + fm * 16 + ln) * 32 + (g ^ rsw) * 8];
#pragma unroll
    for (int fn = 0; fn < 4; ++fn)
      bfr[fn] = *(const short8*)&Bs[(wn * 64 + fn * 16 + ln) * 32 + (g ^ rsw) * 8];
#pragma unroll
    for (int fn = 0; fn < 4; ++fn) {
#pragma unroll
      for (int fm = 0; fm < 4; ++fm) acc[fm][fn] = MFMA16(af[fm], bfr[fn], acc[fm][fn]);
    }
    cur = (cur == 2) ? 0 : cur + 1;
  }
  __syncthreads();
  const float scale = 0.125f * LOG2E;
#pragma unroll
  for (int fn = 0; fn < 4; ++fn) {
    float bn = bq[n0 + wn * 64 + fn * 16 + ln];
#pragma unroll
    for (int fm = 0; fm < 4; ++fm) {
#pragma unroll
      for (int r = 0; r < 4; ++r) {
        float val = (acc[fm][fn][r] + bn) * scale;
        sh[(wm * 64 + fm * 16 + 4 * g + r) * 132 + wn * 64 + fn * 16 + ln] = f2bf(val);
      }
    }
  }
  __syncthreads();
#pragma unroll
  for (int p = 0; p < 16; ++p) {
    int row = p * 8 + (t >> 5), c4 = (t & 31) * 4;
    *(u16x4*)&QW[(size_t)(m0 + row) * 1024 + n0 + c4] =
        *(const u16x4*)&sh[row * 132 + c4];
  }
}

// ---------------------------------------------------------------------------
// Fused K+V projection: A (=VB panel) staged ONCE, two B operands (WtK, WtV),
// 32 MFMA per barrier window. 3-buf ring, 6 loads/tile, vmcnt(6) steady /
// vmcnt(0) tail (ledger verified tt=0,1,30,31). LDS 72KB -> 2 blocks/CU.
// Epilogue: KW tile (bias bk), then VWT transposed tile (bias bv).
// ---------------------------------------------------------------------------
__global__ __launch_bounds__(256) void k_projKV(
    const unsigned short* __restrict__ VB, const unsigned short* __restrict__ WtK,
    const unsigned short* __restrict__ WtV, const float* __restrict__ bk,
    const float* __restrict__ bv, unsigned short* __restrict__ KW,
    unsigned short* __restrict__ VWT) {
  const int m0 = blockIdx.x * 128, n0 = blockIdx.y * 128;
  const int t = threadIdx.x, lane = t & 63, w = t >> 6;
  const int g = lane >> 4, ln = lane & 15;
  const int wm = w >> 1, wn = w & 1;
  __shared__ unsigned short sh[36864];  // 3 bufs x (A 4096 + BK 4096 + BV 4096)
  const int srow = lane >> 2;
  const int sc = (lane & 3) ^ ((lane >> 3) & 3);
  const int rsw = ((ln >> 1) & 3);
  f32x4 accK[4][4] = {}, accV[4][4] = {};
#pragma unroll
  for (int pre = 0; pre < 2; ++pre) {
#pragma unroll
    for (int p = 0; p < 2; ++p) {
      gload16(&VB[(size_t)(m0 + p * 64 + w * 16 + srow) * 1024 + pre * 32 + sc * 8],
              &sh[pre * 12288 + (p * 64 + w * 16) * 32]);
      gload16(&WtK[(size_t)(n0 + p * 64 + w * 16 + srow) * 1024 + pre * 32 + sc * 8],
              &sh[pre * 12288 + 4096 + (p * 64 + w * 16) * 32]);
      gload16(&WtV[(size_t)(n0 + p * 64 + w * 16 + srow) * 1024 + pre * 32 + sc * 8],
              &sh[pre * 12288 + 8192 + (p * 64 + w * 16) * 32]);
    }
  }
  int cur = 0;
  for (int tt = 0; tt < 32; ++tt) {
    if (tt < 31) {
      asm volatile("s_waitcnt vmcnt(6)" ::: "memory");
    } else {
      asm volatile("s_waitcnt vmcnt(0)" ::: "memory");
    }
    __builtin_amdgcn_sched_barrier(0);
    __builtin_amdgcn_s_barrier();
    __builtin_amdgcn_sched_barrier(0);
    if (tt < 30) {
      int bb = cur + 2; if (bb >= 3) bb -= 3;
      int kk = (tt + 2) * 32;
#pragma unroll
      for (int p = 0; p < 2; ++p) {
        gload16(&VB[(size_t)(m0 + p * 64 + w * 16 + srow) * 1024 + kk + sc * 8],
                &sh[bb * 12288 + (p * 64 + w * 16) * 32]);
        gload16(&WtK[(size_t)(n0 + p * 64 + w * 16 + srow) * 1024 + kk + sc * 8],
                &sh[bb * 12288 + 4096 + (p * 64 + w * 16) * 32]);
        gload16(&WtV[(size_t)(n0 + p * 64 + w * 16 + srow) * 1024 + kk + sc * 8],
                &sh[bb * 12288 + 8192 + (p * 64 + w * 16) * 32]);
      }
    }
    const unsigned short* As = &sh[cur * 12288];
    const unsigned short* BKs = As + 4096;
    const unsigned short* BVs = As + 8192;
    short8 af[4], bk8[4], bv8[4];
#pragma unroll
    for (int fm = 0; fm < 4; ++fm)
      af[fm] = *(const short8*)&As[(wm * 64 + fm * 16 + ln) * 32 + (g ^ rsw) * 8];
#pragma unroll
    for (int fn = 0; fn < 4; ++fn) {
      bk8[fn] = *(const short8*)&BKs[(wn * 64 + fn * 16 + ln) * 32 + (g ^ rsw) * 8];
      bv8[fn] = *(const short8*)&BVs[(wn * 64 + fn * 16 + ln) * 32 + (g ^ rsw) * 8];
    }
#pragma unroll
    for (int fn = 0; fn < 4; ++fn) {
#pragma unroll
      for (int fm = 0; fm < 4; ++fm) {
        accK[fm][fn] = MFMA16(af[fm], bk8[fn], accK[fm][fn]);
        accV[fm][fn] = MFMA16(af[fm], bv8[fn], accV[fm][fn]);
      }
    }
    cur = (cur == 2) ? 0 : cur + 1;
  }
  // epilogue 1: KW tile
  __syncthreads();
#pragma unroll
  for (int fn = 0; fn < 4; ++fn) {
    float bn = bk[n0 + wn * 64 + fn * 16 + ln];
#pragma unroll
    for (int fm = 0; fm < 4; ++fm) {
#pragma unroll
      for (int r = 0; r < 4; ++r)
        sh[(wm * 64 + fm * 16 + 4 * g + r) * 132 + wn * 64 + fn * 16 + ln] =
            f2bf(accK[fm][fn][r] + bn);
    }
  }
  __syncthreads();
#pragma unroll
  for (int p = 0; p < 16; ++p) {
    int row = p * 8 + (t >> 5), c4 = (t & 31) * 4;
    *(u16x4*)&KW[(size_t)(m0 + row) * 1024 + n0 + c4] =
        *(const u16x4*)&sh[row * 132 + c4];
  }
  // epilogue 2: VWT transposed tile
  __syncthreads();
#pragma unroll
  for (int fn = 0; fn < 4; ++fn) {
    float bn = bv[n0 + wn * 64 + fn * 16 + ln];
#pragma unroll
    for (int fm = 0; fm < 4; ++fm) {
#pragma unroll
      for (int r = 0; r < 4; ++r)
        sh[(wm * 64 + fm * 16 + 4 * g + r) * 132 + wn * 64 + fn * 16 + ln] =
            f2bf(accV[fm][fn][r] + bn);
    }
  }
  __syncthreads();
  {
    const int b = m0 >> 10, s0 = m0 & 1023;
#pragma unroll
    for (int p = 0; p < 16; ++p) {
#pragma unroll
      for (int qh = 0; qh < 2; ++qh) {
        int hdl = p * 8 + (t >> 5);
        int sl = qh * 64 + (t & 31) * 2;
        unsigned lo = sh[sl * 132 + hdl];
        unsigned hi = sh[(sl + 1) * 132 + hdl];
        int hd = n0 + hdl;
        int h = hd >> 6, d = hd & 63;
        *(unsigned*)&VWT[((size_t)(b * 16 + h) * 64 + d) * 1024 + s0 + sl] =
            lo | (hi << 16);
      }
    }
  }
}

// ---------------------------------------------------------------------------
// Output projection (GEMM3 ring): out = (OB @ Wo + bo) * q_mask  (f32 out)
// ---------------------------------------------------------------------------
__global__ __launch_bounds__(256) void k_out3(
    const unsigned short* __restrict__ OB, const unsigned short* __restrict__ WtO,
    const float* __restrict__ bo, const int* __restrict__ qmask,
    float* __restrict__ out) {
  const int m0 = blockIdx.x * 128, n0 = blockIdx.y * 128;
  const int t = threadIdx.x, lane = t & 63, w = t >> 6;
  const int g = lane >> 4, ln = lane & 15;
  const int wm = w >> 1, wn = w & 1;
  __shared__ unsigned short sh[24576];
  const int srow = lane >> 2;
  const int sc = (lane & 3) ^ ((lane >> 3) & 3);
  const int rsw = ((ln >> 1) & 3);
  f32x4 acc[4][4] = {};
#pragma unroll
  for (int pre = 0; pre < 2; ++pre) {
#pragma unroll
    for (int p = 0; p < 2; ++p) {
      gload16(&OB[(size_t)(m0 + p * 64 + w * 16 + srow) * 1024 + pre * 32 + sc * 8],
              &sh[pre * 8192 + (p * 64 + w * 16) * 32]);
      gload16(&WtO[(size_t)(n0 + p * 64 + w * 16 + srow) * 1024 + pre * 32 + sc * 8],
              &sh[pre * 8192 + 4096 + (p * 64 + w * 16) * 32]);
    }
  }
  int cur = 0;
  for (int tt = 0; tt < 32; ++tt) {
    if (tt < 31) {
      asm volatile("s_waitcnt vmcnt(4)" ::: "memory");
    } else {
      asm volatile("s_waitcnt vmcnt(0)" ::: "memory");
    }
    __builtin_amdgcn_sched_barrier(0);
    __builtin_amdgcn_s_barrier();
    __builtin_amdgcn_sched_barrier(0);
    if (tt < 30) {
      int bb = cur + 2; if (bb >= 3) bb -= 3;
      int kk = (tt + 2) * 32;
#pragma unroll
      for (int p = 0; p < 2; ++p) {
        gload16(&OB[(size_t)(m0 + p * 64 + w * 16 + srow) * 1024 + kk + sc * 8],
                &sh[bb * 8192 + (p * 64 + w * 16) * 32]);
        gload16(&WtO[(size_t)(n0 + p * 64 + w * 16 + srow) * 1024 + kk + sc * 8],
                &sh[bb * 8192 + 4096 + (p * 64 + w * 16) * 32]);
      }
    }
    const unsigned short* As = &sh[cur * 8192];
    const unsigned short* Bs = As + 4096;
    short8 af[4], bfr[4];
#pragma unroll
    for (int fm = 0; fm < 4; ++fm)
      af[fm] = *(const short8*)&As[(wm * 64 + fm * 16 + ln) * 32 + (g ^ rsw) * 8];
#pragma unroll
    for (int fn = 0; fn < 4; ++fn)
      bfr[fn] = *(const short8*)&Bs[(wn * 64 + fn * 16 + ln) * 32 + (g ^ rsw) * 8];
#pragma unroll
    for (int fn = 0; fn < 4; ++fn) {
#pragma unroll
      for (int fm = 0; fm < 4; ++fm) acc[fm][fn] = MFMA16(af[fm], bfr[fn], acc[fm][fn]);
    }
    cur = (cur == 2) ? 0 : cur + 1;
  }
  float bn[4];
#pragma unroll
  for (int fn = 0; fn < 4; ++fn) bn[fn] = bo[n0 + wn * 64 + fn * 16 + ln];
#pragma unroll
  for (int fm = 0; fm < 4; ++fm) {
#pragma unroll
    for (int r = 0; r < 4; ++r) {
      int row = m0 + wm * 64 + fm * 16 + 4 * g + r;
      float qm = (float)qmask[row];
#pragma unroll
      for (int fn = 0; fn < 4; ++fn)
        out[(size_t)row * 1024 + n0 + wn * 64 + fn * 16 + ln] =
            (acc[fm][fn][r] + bn[fn]) * qm;
    }
  }
}

// ---------------------------------------------------------------------------
// Position-bias scores, stripe of 512 j: CB[bh][jl 512][k 1024]
// Key mask (-NEG*log2e for masked keys) folded into CB here.
// XCD locality: grid (512 jl, 8 kt) -> same-QW-slab blocks co-XCD.
// ---------------------------------------------------------------------------
__global__ __launch_bounds__(256) void k_pbias(
    const unsigned short* __restrict__ QW, const float* __restrict__ pb,
    const int* __restrict__ vmask, unsigned short* __restrict__ CB, int jbase) {
  const int kt = blockIdx.y;  // 0..7
  const int jl = blockIdx.x;  // 0..511
  const int j = jbase + jl;
  const int t = threadIdx.x, lane = t & 63, w = t >> 6;
  const int g = lane >> 4, ln = lane & 15;
  const int wm = w >> 1, wn = w & 1;
  __shared__ unsigned short sm[18432];
  unsigned short* a_lds = sm;         // [128 bh][72]
  unsigned short* b_lds = sm + 9216;  // [128 k][72]
#pragma unroll
  for (int p = 0; p < 8; ++p) {
    int i4 = p * 256 + t;
    int row = i4 >> 4, c4 = (i4 & 15) * 4;
    *(u16x4*)&a_lds[row * 72 + c4] =
        *(const u16x4*)&QW[((size_t)(row >> 4) * 1024 + j) * 1024 + (row & 15) * 64 + c4];
  }
#pragma unroll
  for (int p = 0; p < 8; ++p) {
    int i4 = p * 256 + t;
    int row = i4 >> 4, c4 = (i4 & 15) * 4;
    fl4 val = *(const fl4*)&pb[((size_t)j * 1024 + kt * 128 + row) * 64 + c4];
    u16x4 u;
    u[0] = f2bf(val[0]); u[1] = f2bf(val[1]);
    u[2] = f2bf(val[2]); u[3] = f2bf(val[3]);
    *(u16x4*)&b_lds[row * 72 + c4] = u;
  }
  __syncthreads();
  f32x4 acc[4][4] = {};
#pragma unroll
  for (int ks = 0; ks < 2; ++ks) {
    short8 af[4];
#pragma unroll
    for (int fm = 0; fm < 4; ++fm)
      af[fm] = *(const short8*)&a_lds[(wm * 64 + fm * 16 + ln) * 72 + ks * 32 + 8 * g];
#pragma unroll
    for (int fn = 0; fn < 4; ++fn) {
      short8 bfr = *(const short8*)&b_lds[(wn * 64 + fn * 16 + ln) * 72 + ks * 32 + 8 * g];
#pragma unroll
      for (int fm = 0; fm < 4; ++fm) acc[fm][fn] = MFMA16(af[fm], bfr, acc[fm][fn]);
    }
  }
  __syncthreads();
#pragma unroll
  for (int fn = 0; fn < 4; ++fn) {
    int kcol = kt * 128 + wn * 64 + fn * 16 + ln;
#pragma unroll
    for (int fm = 0; fm < 4; ++fm) {
      // b of output row (bh = wm*64+fm*16+4g+r): b = bh>>4 = wm*4+fm
      float off = vmask[(wm * 4 + fm) * 1024 + kcol] ? 0.f : (-1e12f * LOG2E);
#pragma unroll
      for (int r = 0; r < 4; ++r)
        sm[(wm * 64 + fm * 16 + 4 * g + r) * 132 + wn * 64 + fn * 16 + ln] =
            f2bf(acc[fm][fn][r] + off);
    }
  }
  __syncthreads();
#pragma unroll
  for (int p = 0; p < 16; ++p) {
    int row = p * 8 + (t >> 5), c4 = (t & 31) * 4;
    *(u16x4*)&CB[((size_t)row * 512 + jl) * 1024 + kt * 128 + c4] =
        *(const u16x4*)&sm[row * 132 + c4];
  }
}

// ---------------------------------------------------------------------------
// Flash attention v5 (unchanged from R14/R15): 32x32x16 MFMA, 64-key tiles,
// 32KB double-buffered LDS, gload_lds staging, counted vmcnt BEFORE barrier,
// permlane32 P-network, XCD swizzle.
// ---------------------------------------------------------------------------
__global__ __launch_bounds__(256) void k_attn(
    const unsigned short* __restrict__ QW, const unsigned short* __restrict__ KW,
    const unsigned short* __restrict__ VWT, const unsigned short* __restrict__ CB,
    unsigned short* __restrict__ OB, int jbase) {
  // XCD swizzle: hw id B -> work w = (B%8)*64 + B/8  (bijective, 512 blocks)
  const int B = blockIdx.x;
  const int wrk = (B & 7) * 64 + (B >> 3);
  const int jt = wrk & 3, h = (wrk >> 2) & 15, b = wrk >> 6;
  const int t = threadIdx.x, lane = t & 63, w = t >> 6;
  const int l31 = lane & 31, hf = lane >> 5;
  const int j0 = jbase + jt * 128 + w * 32;  // wave's first j (global)
  const int jl0 = jt * 128 + w * 32;         // stripe-local
  __shared__ unsigned short lds_kv[2][8192];  // per buf: K [64][64] + V^T [64][64]
  short8 qf[4];
  {
    const size_t qrow = ((size_t)b * 1024 + (j0 + l31)) * 1024 + h * 64;
#pragma unroll
    for (int ds = 0; ds < 4; ++ds)
      qf[ds] = *(const short8*)&QW[qrow + ds * 16 + 8 * hf];
  }
  const size_t cb_row = ((size_t)(b * 16 + h) * 512 + jl0 + l31) * 1024;

  // staging: row = r*32 + w*8 + (lane>>3); chunk swz key = row&7 = (lane>>3)&7
  const int src_row = w * 8 + (lane >> 3);
  const int sc = (lane & 7) ^ ((lane >> 3) & 7);
  const int rk8 = l31 & 7;  // read swz key (row&7 for both K and V reads)

#define STAGE(kt_, bi)                                                            \
  {                                                                               \
    _Pragma("unroll") for (int r = 0; r < 2; ++r) {                               \
      gload16(&KW[((size_t)b * 1024 + (kt_) * 64 + r * 32 + src_row) * 1024 +     \
                  h * 64 + sc * 8],                                               \
              &lds_kv[bi][r * 2048 + w * 512 + lane * 8]);                        \
      gload16(&VWT[(((size_t)(b * 16 + h)) * 64 + r * 32 + src_row) * 1024 +      \
                   (kt_) * 64 + sc * 8],                                          \
              &lds_kv[bi][4096 + r * 2048 + w * 512 + lane * 8]);                 \
    }                                                                             \
  }

  u16x4 rcb[8];
#define LOAD_CB(kt_)                                                              \
  {                                                                               \
    _Pragma("unroll") for (int kf = 0; kf < 2; ++kf) {                            \
      _Pragma("unroll") for (int q = 0; q < 4; ++q)                               \
          rcb[kf * 4 + q] = *(const u16x4*)&CB[cb_row + (kt_) * 64 + kf * 32 +    \
                                               q * 8 + 4 * hf];                   \
    }                                                                             \
  }

  // prologue: STAGE(0), rcb(0), STAGE(1)  (order matters for vmcnt ledger)
  STAGE(0, 0);
  __builtin_amdgcn_sched_barrier(0);
  LOAD_CB(0);
  __builtin_amdgcn_sched_barrier(0);
  STAGE(1, 1);
  __builtin_amdgcn_sched_barrier(0);

  f32x16 o_acc[2] = {};
  float l_par = 0.f;

  for (int kt = 0; kt < 16; ++kt) {
    // confirm OWN stage(kt) retired BEFORE the rendezvous; stage(kt+1)+rcb
    // stay in flight across the barrier.
    if (kt == 0) {
      asm volatile("s_waitcnt vmcnt(12)" ::: "memory");
    } else {
      asm volatile("s_waitcnt vmcnt(8)" ::: "memory");
    }
    __builtin_amdgcn_sched_barrier(0);
    __builtin_amdgcn_s_barrier();
    __builtin_amdgcn_sched_barrier(0);
    if (kt >= 1 && kt < 15) STAGE(kt + 1, (kt + 1) & 1);
    __builtin_amdgcn_sched_barrier(0);
    // S^T init from prefetched CB: frag kf reg (q*4+r) = k kf*32+8q+4hf+r
    f32x16 st[2];
#pragma unroll
    for (int kf = 0; kf < 2; ++kf) {
#pragma unroll
      for (int q = 0; q < 4; ++q) {
#pragma unroll
        for (int r = 0; r < 4; ++r) st[kf][q * 4 + r] = bf2f(rcb[kf * 4 + q][r]);
      }
    }
    if (kt < 15) LOAD_CB(kt + 1);
    __builtin_amdgcn_sched_barrier(0);
    const unsigned short* Kb = lds_kv[kt & 1];
    const unsigned short* Vb = Kb + 4096;
    // S^T += K x Q  (A = K frag: row kf*32+l31, d chunk 2ds+hf, swz ^row&7)
    __builtin_amdgcn_s_setprio(1);
#pragma unroll
    for (int ds = 0; ds < 4; ++ds) {
#pragma unroll
      for (int kf = 0; kf < 2; ++kf) {
        short8 af =
            *(const short8*)&Kb[(kf * 32 + l31) * 64 + (((ds * 2 + hf) ^ rk8) * 8)];
        st[kf] = MFMA32(af, qf[ds], st[kf]);
      }
    }
    __builtin_amdgcn_s_setprio(0);
    // Per 16-k step: exp -> pk2 -> 2x permlane32_swap -> PV MFMA. No P LDS.
#pragma unroll
    for (int ks = 0; ks < 4; ++ks) {
      const int kf = ks >> 1, bs = (ks & 1) * 8;
      float e0 = fexp2(st[kf][bs + 0] - 17.0f), e1 = fexp2(st[kf][bs + 1] - 17.0f);
      float e2 = fexp2(st[kf][bs + 2] - 17.0f), e3 = fexp2(st[kf][bs + 3] - 17.0f);
      float e4 = fexp2(st[kf][bs + 4] - 17.0f), e5 = fexp2(st[kf][bs + 5] - 17.0f);
      float e6 = fexp2(st[kf][bs + 6] - 17.0f), e7 = fexp2(st[kf][bs + 7] - 17.0f);
      l_par += ((e0 + e1) + (e2 + e3)) + ((e4 + e5) + (e6 + e7));
      unsigned A0 = pk2(e0, e1), A1 = pk2(e2, e3);
      unsigned C0 = pk2(e4, e5), C1 = pk2(e6, e7);
      asm("v_permlane32_swap_b32 %0, %1" : "+v"(A0), "+v"(C0));
      asm("v_permlane32_swap_b32 %0, %1" : "+v"(A1), "+v"(C1));
      union { short8 v; unsigned u[4]; } bp;
      bp.u[0] = A0; bp.u[1] = A1; bp.u[2] = C0; bp.u[3] = C1;
      __builtin_amdgcn_s_setprio(1);
#pragma unroll
      for (int df = 0; df < 2; ++df) {
        short8 av = *(const short8*)&Vb[(df * 32 + l31) * 64 +
                                        (((ks * 2 + hf) ^ rk8) * 8)];
        o_acc[df] = MFMA32(av, bp.v, o_acc[df]);
      }
      __builtin_amdgcn_s_setprio(0);
    }
  }
  // row-sum: lane l and l^32 hold complementary k halves of row j
  l_par += __shfl_xor(l_par, 32);
  float inv = 1.0f / l_par;
  const size_t orow = ((size_t)b * 1024 + (j0 + l31)) * 1024 + h * 64;
#pragma unroll
  for (int df = 0; df < 2; ++df) {
#pragma unroll
    for (int q = 0; q < 4; ++q) {
      union { u16x4 v; unsigned u[2]; } uo;
      uo.u[0] = pk2(o_acc[df][q * 4 + 0] * inv, o_acc[df][q * 4 + 1] * inv);
      uo.u[1] = pk2(o_acc[df][q * 4 + 2] * inv, o_acc[df][q * 4 + 3] * inv);
      *(u16x4*)&OB[orow + df * 32 + q * 8 + 4 * hf] = uo.v;  // d = df*32+8q+4hf+r
    }
  }
#undef STAGE
#undef LOAD_CB
}

// ---------------------------------------------------------------------------
extern "C" void kernel_launch(void* const* d_in, const int* in_sizes, int n_in,
                              void* d_out, int out_size, void* d_ws, size_t ws_size,
                              hipStream_t stream) {
  const float* q  = (const float*)d_in[0];
  // d_in[1] = k  -- intentionally unused (reference projects K from v)
  const float* v  = (const float*)d_in[2];
  const float* pb = (const float*)d_in[3];
  const float* Wq = (const float*)d_in[4];
  const float* Wk = (const float*)d_in[5];
  const float* Wv = (const float*)d_in[6];
  const float* Wo = (const float*)d_in[7];
  const float* bq = (const float*)d_in[8];
  const float* bk = (const float*)d_in[9];
  const float* bv = (const float*)d_in[10];
  const float* bo = (const float*)d_in[11];
  const int* qm = (const int*)d_in[12];
  const int* vm = (const int*)d_in[13];
  float* out = (float*)d_out;

  unsigned short* ws = (unsigned short*)d_ws;
  const size_t M1 = 1024 * 1024;
  unsigned short* WTQ = ws;
  unsigned short* WTK = WTQ + M1;
  unsigned short* WTV = WTK + M1;
  unsigned short* WTO = WTV + M1;
  unsigned short* QB  = WTO + M1;              // [8192][1024] bf16(q)
  unsigned short* VB  = QB + 8 * M1;           // [8192][1024] bf16(v)
  unsigned short* QW  = VB + 8 * M1;           // [8192][1024], scaled log2e/8
  unsigned short* KW  = QW + 8 * M1;
  unsigned short* VWT = KW + 8 * M1;           // [b][h][d][s]
  unsigned short* OB  = VWT + 8 * M1;
  unsigned short* CB  = OB + 8 * M1;           // [bh 128][jl 512][k 1024] stripe (134MB)

  k_prep<<<dim3(9216), 256, 0, stream>>>(Wq, Wk, Wv, Wo, WTQ, WTK, WTV, WTO,
                                         q, v, QB, VB);
  k_projQ<<<dim3(64, 8), 256, 0, stream>>>(QB, WTQ, bq, QW);
  k_projKV<<<dim3(64, 8), 256, 0, stream>>>(VB, WTK, WTV, bk, bv, KW, VWT);
  for (int st = 0; st < 2; ++st) {
    k_pbias<<<dim3(512, 8), 256, 0, stream>>>(QW, pb, vm, CB, st * 512);
    k_attn<<<dim3(512), 256, 0, stream>>>(QW, KW, VWT, CB, OB, st * 512);
  }
  k_out3<<<dim3(64, 8), 256, 0, stream>>>(OB, WTO, bo, qm, out);
}

// Round 17
// 335.284 us; speedup vs baseline: 1.0326x; 1.0326x over previous
//
#include <hip/hip_runtime.h>

using short8 = __attribute__((ext_vector_type(8))) short;
using f32x4  = __attribute__((ext_vector_type(4))) float;
using f32x16 = __attribute__((ext_vector_type(16))) float;
using u16x4  = __attribute__((ext_vector_type(4))) unsigned short;
using fl4    = __attribute__((ext_vector_type(4))) float;

#define MFMA16(a, b, c) __builtin_amdgcn_mfma_f32_16x16x32_bf16((a), (b), (c), 0, 0, 0)
#define MFMA32(a, b, c) __builtin_amdgcn_mfma_f32_32x32x16_bf16((a), (b), (c), 0, 0, 0)

static __device__ __forceinline__ unsigned short f2bf(float f) {
  union { float f; unsigned u; } x; x.f = f;
  return (unsigned short)((x.u + 0x7FFFu + ((x.u >> 16) & 1u)) >> 16);
}
static __device__ __forceinline__ float bf2f(unsigned short s) {
  union { unsigned u; float f; } x; x.u = ((unsigned)s) << 16;
  return x.f;
}
// v_exp_f32 computes 2^x directly (input pre-scaled by log2e upstream)
static __device__ __forceinline__ float fexp2(float x) {
  float r; asm("v_exp_f32 %0, %1" : "=v"(r) : "v"(x)); return r;
}
// packed f32x2 -> bf16x2 (RNE), T12 recipe
static __device__ __forceinline__ unsigned pk2(float lo, float hi) {
  unsigned r; asm("v_cvt_pk_bf16_f32 %0, %1, %2" : "=v"(r) : "v"(lo), "v"(hi));
  return r;
}

// async global->LDS, 16B per lane; lds base must be wave-uniform.
static __device__ __forceinline__ void gload16(const void* g, void* l) {
  __builtin_amdgcn_global_load_lds((const __attribute__((address_space(1))) void*)g,
                                   (__attribute__((address_space(3))) void*)l, 16, 0, 0);
}

#define LOG2E 1.4426950408889634f

// ---------------------------------------------------------------------------
// Prep (fused): blocks [0,1024): Wt[n][k]=bf16(W[k][n]) for 4 weights;
//               blocks [1024,9216): f32->bf16 bulk convert of q and v.
// ---------------------------------------------------------------------------
__global__ __launch_bounds__(256) void k_prep(
    const float* __restrict__ W0, const float* __restrict__ W1,
    const float* __restrict__ W2, const float* __restrict__ W3,
    unsigned short* __restrict__ Wt0, unsigned short* __restrict__ Wt1,
    unsigned short* __restrict__ Wt2, unsigned short* __restrict__ Wt3,
    const float* __restrict__ qf, const float* __restrict__ vf,
    unsigned short* __restrict__ QB, unsigned short* __restrict__ VB) {
  __shared__ float tile[64][65];
  const int bx = blockIdx.x;
  const int t = threadIdx.x;
  if (bx < 1024) {
    const int z = bx >> 8, yy = (bx >> 4) & 15, xx = bx & 15;
    const float* W = (z == 0) ? W0 : (z == 1) ? W1 : (z == 2) ? W2 : W3;
    unsigned short* Wt = (z == 0) ? Wt0 : (z == 1) ? Wt1 : (z == 2) ? Wt2 : Wt3;
    const int n0 = xx * 64, k0 = yy * 64;
#pragma unroll
    for (int p = 0; p < 4; ++p) {
      int row = p * 16 + (t >> 4);
      int c4 = (t & 15) * 4;
      fl4 val = *(const fl4*)&W[(size_t)(k0 + row) * 1024 + n0 + c4];
      tile[row][c4 + 0] = val[0];
      tile[row][c4 + 1] = val[1];
      tile[row][c4 + 2] = val[2];
      tile[row][c4 + 3] = val[3];
    }
    __syncthreads();
#pragma unroll
    for (int p = 0; p < 4; ++p) {
      int n = p * 16 + (t >> 4);
      int k4 = (t & 15) * 4;
      u16x4 u;
      u[0] = f2bf(tile[k4 + 0][n]);
      u[1] = f2bf(tile[k4 + 1][n]);
      u[2] = f2bf(tile[k4 + 2][n]);
      u[3] = f2bf(tile[k4 + 3][n]);
      *(u16x4*)&Wt[(size_t)(n0 + n) * 1024 + k0 + k4] = u;
    }
  } else {
    const int idx = bx - 1024;           // 0..8191
    const int half = idx >> 12;          // 0: q, 1: v
    const int blk = idx & 4095;
    const float* src = half ? vf : qf;
    unsigned short* dst = half ? VB : QB;
    size_t i = ((size_t)blk * 256 + t) * 8;
    fl4 v0 = *(const fl4*)&src[i];
    fl4 v1 = *(const fl4*)&src[i + 4];
    u16x4 u0, u1;
    u0[0] = f2bf(v0[0]); u0[1] = f2bf(v0[1]); u0[2] = f2bf(v0[2]); u0[3] = f2bf(v0[3]);
    u1[0] = f2bf(v1[0]); u1[1] = f2bf(v1[1]); u1[2] = f2bf(v1[2]); u1[3] = f2bf(v1[3]);
    *(u16x4*)&dst[i] = u0;
    *(u16x4*)&dst[i + 4] = u1;
  }
}

// ---------------------------------------------------------------------------
// 3-deep pipelined bf16 GEMM core (race-fixed counted-vmcnt)
// ---------------------------------------------------------------------------
#define GEMM3_CORE(APTR, BPTR)                                                  \
  const int t = threadIdx.x, lane = t & 63, w = t >> 6;                         \
  const int g = lane >> 4, ln = lane & 15;                                      \
  const int wm = w >> 1, wn = w & 1;                                            \
  __shared__ unsigned short sh[24576]; /* 3 bufs x (A 4096 + B 4096) elems */   \
  const int srow = lane >> 2;                                                   \
  const int sc = (lane & 3) ^ ((lane >> 3) & 3);                                \
  const int rsw = ((ln >> 1) & 3);                                              \
  f32x4 acc[4][4] = {};                                                         \
  _Pragma("unroll") for (int pre = 0; pre < 2; ++pre) {                         \
    _Pragma("unroll") for (int p = 0; p < 2; ++p) {                             \
      gload16(&APTR[(size_t)(m0 + p * 64 + w * 16 + srow) * 1024 + pre * 32 + sc * 8], \
              &sh[pre * 8192 + (p * 64 + w * 16) * 32]);                        \
      gload16(&BPTR[(size_t)(n0 + p * 64 + w * 16 + srow) * 1024 + pre * 32 + sc * 8], \
              &sh[pre * 8192 + 4096 + (p * 64 + w * 16) * 32]);                 \
    }                                                                           \
  }                                                                             \
  int cur = 0;                                                                  \
  for (int tt = 0; tt < 32; ++tt) {                                             \
    if (tt < 31) {                                                              \
      asm volatile("s_waitcnt vmcnt(4)" ::: "memory");                          \
    } else {                                                                    \
      asm volatile("s_waitcnt vmcnt(0)" ::: "memory");                          \
    }                                                                           \
    __builtin_amdgcn_sched_barrier(0);                                          \
    __builtin_amdgcn_s_barrier();                                               \
    __builtin_amdgcn_sched_barrier(0);                                          \
    if (tt < 30) {                                                              \
      int bb = cur + 2; if (bb >= 3) bb -= 3;                                   \
      int kk = (tt + 2) * 32;                                                   \
      _Pragma("unroll") for (int p = 0; p < 2; ++p) {                           \
        gload16(&APTR[(size_t)(m0 + p * 64 + w * 16 + srow) * 1024 + kk + sc * 8], \
                &sh[bb * 8192 + (p * 64 + w * 16) * 32]);                       \
        gload16(&BPTR[(size_t)(n0 + p * 64 + w * 16 + srow) * 1024 + kk + sc * 8], \
                &sh[bb * 8192 + 4096 + (p * 64 + w * 16) * 32]);                \
      }                                                                         \
    }                                                                           \
    const unsigned short* As = &sh[cur * 8192];                                 \
    const unsigned short* Bs = As + 4096;                                       \
    short8 af[4], bfr[4];                                                       \
    _Pragma("unroll") for (int fm = 0; fm < 4; ++fm)                            \
        af[fm] = *(const short8*)&As[(wm * 64 + fm * 16 + ln) * 32 + (g ^ rsw) * 8]; \
    _Pragma("unroll") for (int fn = 0; fn < 4; ++fn)                            \
        bfr[fn] = *(const short8*)&Bs[(wn * 64 + fn * 16 + ln) * 32 + (g ^ rsw) * 8]; \
    _Pragma("unroll") for (int fn = 0; fn < 4; ++fn) {                          \
      _Pragma("unroll") for (int fm = 0; fm < 4; ++fm)                          \
          acc[fm][fn] = MFMA16(af[fm], bfr[fn], acc[fm][fn]);                   \
    }                                                                           \
    cur = (cur == 2) ? 0 : cur + 1;                                             \
  }

// ---------------------------------------------------------------------------
// Projections (pipelined): mode 0=QW (scaled log2e/8), 1=KW, 2=VWT
// XCD locality: grid (64 m0, 8 n0, 3) -> same-A blocks co-XCD (R15 best).
// ---------------------------------------------------------------------------
__global__ __launch_bounds__(256) void k_proj3(
    const unsigned short* __restrict__ QB, const unsigned short* __restrict__ VB,
    const unsigned short* __restrict__ WtQ, const unsigned short* __restrict__ WtK,
    const unsigned short* __restrict__ WtV,
    const float* __restrict__ bq, const float* __restrict__ bk,
    const float* __restrict__ bv,
    unsigned short* __restrict__ QW, unsigned short* __restrict__ KW,
    unsigned short* __restrict__ VWT) {
  const int mode = blockIdx.z;
  const unsigned short* A8 = (mode == 0) ? QB : VB;
  const unsigned short* Wt = (mode == 0) ? WtQ : (mode == 1) ? WtK : WtV;
  const float* bias = (mode == 0) ? bq : (mode == 1) ? bk : bv;
  const int m0 = blockIdx.x * 128, n0 = blockIdx.y * 128;
  GEMM3_CORE(A8, Wt)
  __syncthreads();
  const float scale = (mode == 0) ? (0.125f * LOG2E) : 1.0f;
#pragma unroll
  for (int fn = 0; fn < 4; ++fn) {
    float bn = bias[n0 + wn * 64 + fn * 16 + ln];
#pragma unroll
    for (int fm = 0; fm < 4; ++fm) {
#pragma unroll
      for (int r = 0; r < 4; ++r) {
        float val = (acc[fm][fn][r] + bn) * scale;
        sh[(wm * 64 + fm * 16 + 4 * g + r) * 132 + wn * 64 + fn * 16 + ln] = f2bf(val);
      }
    }
  }
  __syncthreads();
  if (mode < 2) {
    unsigned short* OUT = (mode == 0) ? QW : KW;
#pragma unroll
    for (int p = 0; p < 16; ++p) {
      int row = p * 8 + (t >> 5), c4 = (t & 31) * 4;
      *(u16x4*)&OUT[(size_t)(m0 + row) * 1024 + n0 + c4] =
          *(const u16x4*)&sh[row * 132 + c4];
    }
  } else {
    const int b = m0 >> 10, s0 = m0 & 1023;
#pragma unroll
    for (int p = 0; p < 16; ++p) {
#pragma unroll
      for (int qh = 0; qh < 2; ++qh) {
        int hdl = p * 8 + (t >> 5);
        int sl = qh * 64 + (t & 31) * 2;
        unsigned lo = sh[sl * 132 + hdl];
        unsigned hi = sh[(sl + 1) * 132 + hdl];
        int hd = n0 + hdl;
        int h = hd >> 6, d = hd & 63;
        *(unsigned*)&VWT[((size_t)(b * 16 + h) * 64 + d) * 1024 + s0 + sl] =
            lo | (hi << 16);
      }
    }
  }
}

// ---------------------------------------------------------------------------
// Output projection (pipelined): out = (OB @ Wo + bo) * q_mask  (f32 out)
// XCD locality: grid (64 m0, 8 n0) -> same-A (OB-tile) blocks co-XCD.
// ---------------------------------------------------------------------------
__global__ __launch_bounds__(256) void k_out3(
    const unsigned short* __restrict__ OB, const unsigned short* __restrict__ WtO,
    const float* __restrict__ bo, const int* __restrict__ qmask,
    float* __restrict__ out) {
  const int m0 = blockIdx.x * 128, n0 = blockIdx.y * 128;
  GEMM3_CORE(OB, WtO)
  float bn[4];
#pragma unroll
  for (int fn = 0; fn < 4; ++fn) bn[fn] = bo[n0 + wn * 64 + fn * 16 + ln];
#pragma unroll
  for (int fm = 0; fm < 4; ++fm) {
#pragma unroll
    for (int r = 0; r < 4; ++r) {
      int row = m0 + wm * 64 + fm * 16 + 4 * g + r;
      float qm = (float)qmask[row];
#pragma unroll
      for (int fn = 0; fn < 4; ++fn)
        out[(size_t)row * 1024 + n0 + wn * 64 + fn * 16 + ln] =
            (acc[fm][fn][r] + bn[fn]) * qm;
    }
  }
}

// ---------------------------------------------------------------------------
// Position-bias scores, stripe of 512 j: CB[bh][jl 512][k 1024]
// Key mask (-NEG*log2e for masked keys) folded into CB here.
// XCD locality: grid (512 jl, 8 kt) -> same-QW-slab blocks co-XCD.
// ---------------------------------------------------------------------------
__global__ __launch_bounds__(256) void k_pbias(
    const unsigned short* __restrict__ QW, const float* __restrict__ pb,
    const int* __restrict__ vmask, unsigned short* __restrict__ CB, int jbase) {
  const int kt = blockIdx.y;  // 0..7
  const int jl = blockIdx.x;  // 0..511
  const int j = jbase + jl;
  const int t = threadIdx.x, lane = t & 63, w = t >> 6;
  const int g = lane >> 4, ln = lane & 15;
  const int wm = w >> 1, wn = w & 1;
  __shared__ unsigned short sm[18432];
  unsigned short* a_lds = sm;         // [128 bh][72]
  unsigned short* b_lds = sm + 9216;  // [128 k][72]
#pragma unroll
  for (int p = 0; p < 8; ++p) {
    int i4 = p * 256 + t;
    int row = i4 >> 4, c4 = (i4 & 15) * 4;
    *(u16x4*)&a_lds[row * 72 + c4] =
        *(const u16x4*)&QW[((size_t)(row >> 4) * 1024 + j) * 1024 + (row & 15) * 64 + c4];
  }
#pragma unroll
  for (int p = 0; p < 8; ++p) {
    int i4 = p * 256 + t;
    int row = i4 >> 4, c4 = (i4 & 15) * 4;
    fl4 val = *(const fl4*)&pb[((size_t)j * 1024 + kt * 128 + row) * 64 + c4];
    u16x4 u;
    u[0] = f2bf(val[0]); u[1] = f2bf(val[1]);
    u[2] = f2bf(val[2]); u[3] = f2bf(val[3]);
    *(u16x4*)&b_lds[row * 72 + c4] = u;
  }
  __syncthreads();
  f32x4 acc[4][4] = {};
#pragma unroll
  for (int ks = 0; ks < 2; ++ks) {
    short8 af[4];
#pragma unroll
    for (int fm = 0; fm < 4; ++fm)
      af[fm] = *(const short8*)&a_lds[(wm * 64 + fm * 16 + ln) * 72 + ks * 32 + 8 * g];
#pragma unroll
    for (int fn = 0; fn < 4; ++fn) {
      short8 bfr = *(const short8*)&b_lds[(wn * 64 + fn * 16 + ln) * 72 + ks * 32 + 8 * g];
#pragma unroll
      for (int fm = 0; fm < 4; ++fm) acc[fm][fn] = MFMA16(af[fm], bfr, acc[fm][fn]);
    }
  }
  __syncthreads();
#pragma unroll
  for (int fn = 0; fn < 4; ++fn) {
    int kcol = kt * 128 + wn * 64 + fn * 16 + ln;
#pragma unroll
    for (int fm = 0; fm < 4; ++fm) {
      // b of output row (bh = wm*64+fm*16+4g+r): b = bh>>4 = wm*4+fm
      float off = vmask[(wm * 4 + fm) * 1024 + kcol] ? 0.f : (-1e12f * LOG2E);
#pragma unroll
      for (int r = 0; r < 4; ++r)
        sm[(wm * 64 + fm * 16 + 4 * g + r) * 132 + wn * 64 + fn * 16 + ln] =
            f2bf(acc[fm][fn][r] + off);
    }
  }
  __syncthreads();
#pragma unroll
  for (int p = 0; p < 16; ++p) {
    int row = p * 8 + (t >> 5), c4 = (t & 31) * 4;
    *(u16x4*)&CB[((size_t)row * 512 + jl) * 1024 + kt * 128 + c4] =
        *(const u16x4*)&sm[row * 132 + c4];
  }
}

// ---------------------------------------------------------------------------
// Flash attention v5 (R14/R15 best): 32x32x16 MFMA, 64-key tiles, 32KB
// double-buffered LDS, gload_lds staging, counted vmcnt BEFORE barrier,
// permlane32 P-network, XCD swizzle.
// ---------------------------------------------------------------------------
__global__ __launch_bounds__(256) void k_attn(
    const unsigned short* __restrict__ QW, const unsigned short* __restrict__ KW,
    const unsigned short* __restrict__ VWT, const unsigned short* __restrict__ CB,
    unsigned short* __restrict__ OB, int jbase) {
  // XCD swizzle: hw id B -> work w = (B%8)*64 + B/8  (bijective, 512 blocks)
  const int B = blockIdx.x;
  const int wrk = (B & 7) * 64 + (B >> 3);
  const int jt = wrk & 3, h = (wrk >> 2) & 15, b = wrk >> 6;
  const int t = threadIdx.x, lane = t & 63, w = t >> 6;
  const int l31 = lane & 31, hf = lane >> 5;
  const int j0 = jbase + jt * 128 + w * 32;  // wave's first j (global)
  const int jl0 = jt * 128 + w * 32;         // stripe-local
  __shared__ unsigned short lds_kv[2][8192];  // per buf: K [64][64] + V^T [64][64]
  short8 qf[4];
  {
    const size_t qrow = ((size_t)b * 1024 + (j0 + l31)) * 1024 + h * 64;
#pragma unroll
    for (int ds = 0; ds < 4; ++ds)
      qf[ds] = *(const short8*)&QW[qrow + ds * 16 + 8 * hf];
  }
  const size_t cb_row = ((size_t)(b * 16 + h) * 512 + jl0 + l31) * 1024;

  // staging: row = r*32 + w*8 + (lane>>3); chunk swz key = row&7 = (lane>>3)&7
  const int src_row = w * 8 + (lane >> 3);
  const int sc = (lane & 7) ^ ((lane >> 3) & 7);
  const int rk8 = l31 & 7;  // read swz key (row&7 for both K and V reads)

#define STAGE(kt_, bi)                                                            \
  {                                                                               \
    _Pragma("unroll") for (int r = 0; r < 2; ++r) {                               \
      gload16(&KW[((size_t)b * 1024 + (kt_) * 64 + r * 32 + src_row) * 1024 +     \
                  h * 64 + sc * 8],                                               \
              &lds_kv[bi][r * 2048 + w * 512 + lane * 8]);                        \
      gload16(&VWT[(((size_t)(b * 16 + h)) * 64 + r * 32 + src_row) * 1024 +      \
                   (kt_) * 64 + sc * 8],                                          \
              &lds_kv[bi][4096 + r * 2048 + w * 512 + lane * 8]);                 \
    }                                                                             \
  }

  u16x4 rcb[8];
#define LOAD_CB(kt_)                                                              \
  {                                                                               \
    _Pragma("unroll") for (int kf = 0; kf < 2; ++kf) {                            \
      _Pragma("unroll") for (int q = 0; q < 4; ++q)                               \
          rcb[kf * 4 + q] = *(const u16x4*)&CB[cb_row + (kt_) * 64 + kf * 32 +    \
                                               q * 8 + 4 * hf];                   \
    }                                                                             \
  }

  // prologue: STAGE(0), rcb(0), STAGE(1)  (order matters for vmcnt ledger)
  STAGE(0, 0);
  __builtin_amdgcn_sched_barrier(0);
  LOAD_CB(0);
  __builtin_amdgcn_sched_barrier(0);
  STAGE(1, 1);
  __builtin_amdgcn_sched_barrier(0);

  f32x16 o_acc[2] = {};
  float l_par = 0.f;

  for (int kt = 0; kt < 16; ++kt) {
    // confirm OWN stage(kt) retired BEFORE the rendezvous; stage(kt+1)+rcb
    // stay in flight across the barrier.
    if (kt == 0) {
      asm volatile("s_waitcnt vmcnt(12)" ::: "memory");
    } else {
      asm volatile("s_waitcnt vmcnt(8)" ::: "memory");
    }
    __builtin_amdgcn_sched_barrier(0);
    __builtin_amdgcn_s_barrier();
    __builtin_amdgcn_sched_barrier(0);
    if (kt >= 1 && kt < 15) STAGE(kt + 1, (kt + 1) & 1);
    __builtin_amdgcn_sched_barrier(0);
    // S^T init from prefetched CB: frag kf reg (q*4+r) = k kf*32+8q+4hf+r
    f32x16 st[2];
#pragma unroll
    for (int kf = 0; kf < 2; ++kf) {
#pragma unroll
      for (int q = 0; q < 4; ++q) {
#pragma unroll
        for (int r = 0; r < 4; ++r) st[kf][q * 4 + r] = bf2f(rcb[kf * 4 + q][r]);
      }
    }
    if (kt < 15) LOAD_CB(kt + 1);
    __builtin_amdgcn_sched_barrier(0);
    const unsigned short* Kb = lds_kv[kt & 1];
    const unsigned short* Vb = Kb + 4096;
    // S^T += K x Q  (A = K frag: row kf*32+l31, d chunk 2ds+hf, swz ^row&7)
    __builtin_amdgcn_s_setprio(1);
#pragma unroll
    for (int ds = 0; ds < 4; ++ds) {
#pragma unroll
      for (int kf = 0; kf < 2; ++kf) {
        short8 af =
            *(const short8*)&Kb[(kf * 32 + l31) * 64 + (((ds * 2 + hf) ^ rk8) * 8)];
        st[kf] = MFMA32(af, qf[ds], st[kf]);
      }
    }
    __builtin_amdgcn_s_setprio(0);
    // Per 16-k step: exp -> pk2 -> 2x permlane32_swap -> PV MFMA. No P LDS.
#pragma unroll
    for (int ks = 0; ks < 4; ++ks) {
      const int kf = ks >> 1, bs = (ks & 1) * 8;
      float e0 = fexp2(st[kf][bs + 0] - 17.0f), e1 = fexp2(st[kf][bs + 1] - 17.0f);
      float e2 = fexp2(st[kf][bs + 2] - 17.0f), e3 = fexp2(st[kf][bs + 3] - 17.0f);
      float e4 = fexp2(st[kf][bs + 4] - 17.0f), e5 = fexp2(st[kf][bs + 5] - 17.0f);
      float e6 = fexp2(st[kf][bs + 6] - 17.0f), e7 = fexp2(st[kf][bs + 7] - 17.0f);
      l_par += ((e0 + e1) + (e2 + e3)) + ((e4 + e5) + (e6 + e7));
      unsigned A0 = pk2(e0, e1), A1 = pk2(e2, e3);
      unsigned C0 = pk2(e4, e5), C1 = pk2(e6, e7);
      asm("v_permlane32_swap_b32 %0, %1" : "+v"(A0), "+v"(C0));
      asm("v_permlane32_swap_b32 %0, %1" : "+v"(A1), "+v"(C1));
      union { short8 v; unsigned u[4]; } bp;
      bp.u[0] = A0; bp.u[1] = A1; bp.u[2] = C0; bp.u[3] = C1;
      __builtin_amdgcn_s_setprio(1);
#pragma unroll
      for (int df = 0; df < 2; ++df) {
        short8 av = *(const short8*)&Vb[(df * 32 + l31) * 64 +
                                        (((ks * 2 + hf) ^ rk8) * 8)];
        o_acc[df] = MFMA32(av, bp.v, o_acc[df]);
      }
      __builtin_amdgcn_s_setprio(0);
    }
  }
  // row-sum: lane l and l^32 hold complementary k halves of row j
  l_par += __shfl_xor(l_par, 32);
  float inv = 1.0f / l_par;
  const size_t orow = ((size_t)b * 1024 + (j0 + l31)) * 1024 + h * 64;
#pragma unroll
  for (int df = 0; df < 2; ++df) {
#pragma unroll
    for (int q = 0; q < 4; ++q) {
      union { u16x4 v; unsigned u[2]; } uo;
      uo.u[0] = pk2(o_acc[df][q * 4 + 0] * inv, o_acc[df][q * 4 + 1] * inv);
      uo.u[1] = pk2(o_acc[df][q * 4 + 2] * inv, o_acc[df][q * 4 + 3] * inv);
      *(u16x4*)&OB[orow + df * 32 + q * 8 + 4 * hf] = uo.v;  // d = df*32+8q+4hf+r
    }
  }
#undef STAGE
#undef LOAD_CB
}

// ---------------------------------------------------------------------------
extern "C" void kernel_launch(void* const* d_in, const int* in_sizes, int n_in,
                              void* d_out, int out_size, void* d_ws, size_t ws_size,
                              hipStream_t stream) {
  const float* q  = (const float*)d_in[0];
  // d_in[1] = k  -- intentionally unused (reference projects K from v)
  const float* v  = (const float*)d_in[2];
  const float* pb = (const float*)d_in[3];
  const float* Wq = (const float*)d_in[4];
  const float* Wk = (const float*)d_in[5];
  const float* Wv = (const float*)d_in[6];
  const float* Wo = (const float*)d_in[7];
  const float* bq = (const float*)d_in[8];
  const float* bk = (const float*)d_in[9];
  const float* bv = (const float*)d_in[10];
  const float* bo = (const float*)d_in[11];
  const int* qm = (const int*)d_in[12];
  const int* vm = (const int*)d_in[13];
  float* out = (float*)d_out;

  unsigned short* ws = (unsigned short*)d_ws;
  const size_t M1 = 1024 * 1024;
  unsigned short* WTQ = ws;
  unsigned short* WTK = WTQ + M1;
  unsigned short* WTV = WTK + M1;
  unsigned short* WTO = WTV + M1;
  unsigned short* QB  = WTO + M1;              // [8192][1024] bf16(q)
  unsigned short* VB  = QB + 8 * M1;           // [8192][1024] bf16(v)
  unsigned short* QW  = VB + 8 * M1;           // [8192][1024], scaled log2e/8
  unsigned short* KW  = QW + 8 * M1;
  unsigned short* VWT = KW + 8 * M1;           // [b][h][d][s]
  unsigned short* OB  = VWT + 8 * M1;
  unsigned short* CB  = OB + 8 * M1;           // [bh 128][jl 512][k 1024] stripe (134MB)

  k_prep<<<dim3(9216), 256, 0, stream>>>(Wq, Wk, Wv, Wo, WTQ, WTK, WTV, WTO,
                                         q, v, QB, VB);
  k_proj3<<<dim3(64, 8, 3), 256, 0, stream>>>(QB, VB, WTQ, WTK, WTV, bq, bk, bv,
                                              QW, KW, VWT);
  for (int st = 0; st < 2; ++st) {
    k_pbias<<<dim3(512, 8), 256, 0, stream>>>(QW, pb, vm, CB, st * 512);
    k_attn<<<dim3(512), 256, 0, stream>>>(QW, KW, VWT, CB, OB, st * 512);
  }
  k_out3<<<dim3(64, 8), 256, 0, stream>>>(OB, WTO, bo, qm, out);
}